// Round 13
// baseline (84.851 us; speedup 1.0000x reference)
//
#include <hip/hip_runtime.h>
#include <float.h>

// E=4, L=8, S=512, F=32, G=512. KDE via linear-binned histogram + Gaussian
// convolution (exp count ~2R/block). R13 = R10 (best, 82.4us) + float-atomic
// splat with 1/len folded (deletes the int->float convert pass).

#if __has_builtin(__builtin_amdgcn_exp2f)
__device__ __forceinline__ float fast_exp2(float x) { return __builtin_amdgcn_exp2f(x); }
#else
__device__ __forceinline__ float fast_exp2(float x) { return exp2f(x); }
#endif

#define MAXR 150     // max conv radius (bins); runtime R = ceil(3.5/h) ~ 67
#define PADL 160     // zero padding each side of the 513 hist bins
#define HW   840     // hist row width: PADL + 513 + PADR
#define WOFF 163     // center of symmetric weight table (aligned float4 chunks)
#define WFULL 336    // weight table floats (84 float4)

// ---- workspace layout (float offsets) ----
#define PT_OFF    0        // proj^T [E][L][F][S] = 524288 floats (unscaled)
#define SX_OFF    524288   // [256 blk][32 f] sum(x)
#define SXX_OFF   532480   // [256 blk][32 f] sum(x^2)
#define MIN_OFF   540672   // [256] per-block min
#define MAX_OFF   540928   // [256] per-block max
#define CNT_OFF   541184   // completion counter (int)

// ---------- K1: proj^T + std partials + min/max (known-good, absmax 0.0) ----------
__global__ __launch_bounds__(256) void stage_prep(const float* __restrict__ matrix,
                                                  const float* __restrict__ params,
                                                  float* __restrict__ PT,
                                                  float* __restrict__ sxg,
                                                  float* __restrict__ sxxg,
                                                  float* __restrict__ minp,
                                                  float* __restrict__ maxp,
                                                  int* __restrict__ counter) {
    __shared__ float M[64][33];    // +1 pad: proj pass reads column-wise
    __shared__ float Pm[32][32];
    __shared__ float sxr[8][32], sxxr[8][32];
    __shared__ float rmin[4], rmax[4];
    const int bid = blockIdx.x;        // (e*8+l)*8 + stile
    const int s0 = (bid & 7) << 6;
    const int el = bid >> 3;
    const int t = threadIdx.x;
    if (bid == 0 && t == 0) *counter = 0;   // reset for K2's last-block trick
    {
        const float4 v = reinterpret_cast<const float4*>(params)[t];
        const int base = t << 2;
        Pm[base >> 5][base & 31]       = v.x;
        Pm[base >> 5][(base & 31) + 1] = v.y;
        Pm[base >> 5][(base & 31) + 2] = v.z;
        Pm[base >> 5][(base & 31) + 3] = v.w;
    }
    const float4* mb4 = reinterpret_cast<const float4*>(matrix + (size_t)(el * 512 + s0) * 32);
    #pragma unroll
    for (int k = t; k < 512; k += 256) {
        const float4 v = mb4[k];
        const int base = k << 2;
        M[base >> 5][base & 31]       = v.x;
        M[base >> 5][(base & 31) + 1] = v.y;
        M[base >> 5][(base & 31) + 2] = v.z;
        M[base >> 5][(base & 31) + 3] = v.w;
    }
    __syncthreads();
    {
        const int f = t & 31, r = t >> 5;
        float sx = 0.f, sxx = 0.f;
        #pragma unroll
        for (int k = 0; k < 8; ++k) {
            float v = M[r * 8 + k][f];
            sx += v; sxx += v * v;
        }
        sxr[r][f] = sx; sxxr[r][f] = sxx;
    }
    const int s = t & 63;
    const int g0 = t >> 6;
    float lmin = FLT_MAX, lmax = -FLT_MAX;
    #pragma unroll
    for (int pass = 0; pass < 8; ++pass) {
        const int g = (pass << 2) + g0;
        float acc = 0.f;
        #pragma unroll
        for (int fp = 0; fp < 32; ++fp) acc += M[s][fp] * Pm[fp][g];
        lmin = fminf(lmin, acc);
        lmax = fmaxf(lmax, acc);
        PT[(size_t)(el * 32 + g) * 512 + s0 + s] = acc;
    }
    #pragma unroll
    for (int off = 32; off >= 1; off >>= 1) {
        lmin = fminf(lmin, __shfl_xor(lmin, off, 64));
        lmax = fmaxf(lmax, __shfl_xor(lmax, off, 64));
    }
    if ((t & 63) == 0) { rmin[t >> 6] = lmin; rmax[t >> 6] = lmax; }
    __syncthreads();
    if (t < 32) {
        float a = 0.f, b = 0.f;
        #pragma unroll
        for (int r = 0; r < 8; ++r) { a += sxr[r][t]; b += sxxr[r][t]; }
        sxg[bid * 32 + t] = a;
        sxxg[bid * 32 + t] = b;
    }
    if (t == 0) {
        minp[bid] = fminf(fminf(rmin[0], rmin[1]), fminf(rmin[2], rmin[3]));
        maxp[bid] = fmaxf(fmaxf(rmax[0], rmax[1]), fmaxf(rmax[2], rmax[3]));
    }
}

// ---------- K2: consts + float-atomic splat + vectorized Gaussian conv + outputs ----------
// 256 blocks = one per (l,f); 512 threads = (e = t>>7, idx = t&127).
__global__ __launch_bounds__(512) void stage_kde3(const float* __restrict__ PT,
                                                  const float* __restrict__ sxg,
                                                  const float* __restrict__ sxxg,
                                                  const float* __restrict__ minp,
                                                  const float* __restrict__ maxp,
                                                  const int* __restrict__ dlen,
                                                  int* __restrict__ counter,
                                                  float* __restrict__ out) {
    __shared__ __align__(16) float histF[4][HW];  // float bins (ds_add_f32 atomics)
    __shared__ __align__(16) float fine[4][512];  // red values on the fine grid
    __shared__ __align__(16) float wfull[WFULL];  // symmetric weights, zero-padded
    __shared__ float wsum[8], wmn[8], wmx[8];
    __shared__ float wred[8][6];
    __shared__ float csh[8];
    __shared__ int   Rsh;
    __shared__ int   lensh[4];
    __shared__ int   lastf;
    const int t = threadIdx.x;
    const int lf = blockIdx.x;
    const int l = lf >> 5, f = lf & 31;

    if (t < 4) lensh[t] = dlen[(t << 3) + l];
    {   // zero histogram (pads included)
        float* hflat = &histF[0][0];
        #pragma unroll
        for (int k = t; k < 4 * HW; k += 512) hflat[k] = 0.f;
    }

    // ---- consts: every block redundantly reduces K1's tiny partials ----
    {
        float sf = 0.f;
        #pragma unroll
        for (int tr = t; tr < 1024; tr += 512) {     // (e,l,f) triples
            const int el = tr >> 5, fc = tr & 31;
            const int base = el * 256 + fc;
            float Sx = 0.f, Sxx = 0.f;
            #pragma unroll
            for (int tile = 0; tile < 8; ++tile) { Sx += sxg[base + tile * 32]; Sxx += sxxg[base + tile * 32]; }
            const float mean = Sx * (1.0f / 512.0f);
            const float var = (Sxx - Sx * mean) * (1.0f / 511.0f);   // ddof=1
            sf += sqrtf(fmaxf(var, 0.f));
        }
        float mn = (t < 256) ? minp[t] : FLT_MAX;
        float mx = (t < 256) ? maxp[t] : -FLT_MAX;
        #pragma unroll
        for (int off = 32; off >= 1; off >>= 1) {
            sf += __shfl_xor(sf, off, 64);
            mn = fminf(mn, __shfl_xor(mn, off, 64));
            mx = fmaxf(mx, __shfl_xor(mx, off, 64));
        }
        if ((t & 63) == 0) { wsum[t >> 6] = sf; wmn[t >> 6] = mn; wmx[t >> 6] = mx; }
        __syncthreads();
        if (t == 0) {
            float s = 0.f, lo = FLT_MAX, hi = -FLT_MAX;
            #pragma unroll
            for (int w = 0; w < 8; ++w) {
                s += wsum[w]; lo = fminf(lo, wmn[w]); hi = fmaxf(hi, wmx[w]);
            }
            const float stdv = s * (1.0f / 1024.0f);
            const float left  = lo / stdv;
            const float right = hi / stdv;
            const float bw = 1.06f * 0.28717458874925877f;     // mean(std(m)) == 1
            const float delta = (right - left) * (1.0f / 512.0f);
            const float gstep = (right - left) * (1.0f / 511.0f);
            const float divisor = 2.5066282746310002f * bw;
            const float cpos = (0.5f / (bw * bw)) * 1.4426950408889634f;
            const float kf = sqrtf(cpos);          // kernel = exp2(-((x-p)*kf)^2)
            const float h = gstep * kf;            // grid step in scaled units
            csh[0] = left * kf;                    // leftk
            csh[1] = h;
            csh[2] = (1.0f / stdv) * kf;           // xscale
            csh[3] = delta * 0.5f / divisor;       // final scale
            csh[5] = 1.0f / h;                     // invh
            Rsh = min((int)(3.5f / h) + 1, MAXR);  // truncation: tail ~1e-5
        }
    }
    __syncthreads();
    const float h = csh[1];
    const int R = Rsh;

    // ---- symmetric weight table (zero-padded), the ONLY exps in the kernel ----
    if (t < WFULL) {
        const int d = t - WOFF;
        const int ad = (d < 0) ? -d : d;
        const float u = (float)ad * h;
        wfull[t] = (ad <= R) ? fast_exp2(-(u * u)) : 0.f;
    }

    // ---- linear splat into float bins, 1/len folded in ----
    const int e = t >> 7;
    const int idx = t & 127;
    {
        const int sbase = idx << 2;
        const int lenE = lensh[e];
        const float invLen = 1.0f / (float)lenE;
        const size_t row = ((size_t)(((e << 3) + l) * 32 + f) << 9);
        const float4 xv = *reinterpret_cast<const float4*>(&PT[row + sbase]);
        const float A = csh[2] * csh[5];           // u = raw*A - B  in bin units
        const float B = csh[0] * csh[5];
        float uu[4] = { fmaf(xv.x, A, -B), fmaf(xv.y, A, -B),
                        fmaf(xv.z, A, -B), fmaf(xv.w, A, -B) };
        #pragma unroll
        for (int q = 0; q < 4; ++q) {
            if (sbase + q < lenE) {
                const float u = fminf(fmaxf(uu[q], 0.f), 511.f);
                const int   b = (int)u;
                const float fr = u - (float)b;
                atomicAdd(&histF[e][PADL + b], (1.f - fr) * invLen);
                atomicAdd(&histF[e][PADL + b + 1], fr * invLen);
            }
        }
    }
    __syncthreads();

    // ---- vectorized conv: thread = (e, idx), 4 adjacent fine points 4*idx+j ----
    {
        const float4* __restrict__ hf4 =
            reinterpret_cast<const float4*>(&histF[e][0]);   // HW%4==0, aligned
        const float4* __restrict__ wf4 = reinterpret_cast<const float4*>(&wfull[0]);
        const int hbase = 40 + idx;            // (PADL + 4*idx) / 4
        const int i_lo = -((R + 3) >> 2) - 1;
        const int i_hi = (R + 3) >> 2;
        float o0 = 0.f, o1 = 0.f, o2 = 0.f, o3 = 0.f;
        float4 W0 = wf4[40 + i_lo];            // (WOFF-3+4*i)/4 = 40+i
        for (int i = i_lo; i <= i_hi; ++i) {
            const float4 W1 = wf4[41 + i];
            const float4 H = hf4[hbase + i];
            // weight(m,j) = wfull[WOFF + 4i + m - j]; q = m-j+3 -> W0[q<4], W1[q-4]
            o0 += H.x * W0.w + H.y * W1.x + H.z * W1.y + H.w * W1.z;
            o1 += H.x * W0.z + H.y * W0.w + H.z * W1.x + H.w * W1.y;
            o2 += H.x * W0.y + H.y * W0.z + H.z * W0.w + H.w * W1.x;
            o3 += H.x * W0.x + H.y * W0.y + H.z * W0.z + H.w * W0.w;
            W0 = W1;
        }
        *reinterpret_cast<float4*>(&fine[e][idx << 2]) = make_float4(o0, o1, o2, o3);
    }
    __syncthreads();

    // ---- pairwise |diff| summed over g, all in-block ----
    {
        const float r0 = fine[0][t], r1 = fine[1][t], r2 = fine[2][t], r3 = fine[3][t];
        float pr[6];
        pr[0] = fabsf(r0 - r1);
        pr[1] = fabsf(r0 - r2);
        pr[2] = fabsf(r0 - r3);
        pr[3] = fabsf(r1 - r2);
        pr[4] = fabsf(r1 - r3);
        pr[5] = fabsf(r2 - r3);
        #pragma unroll
        for (int pi = 0; pi < 6; ++pi) {
            float v = pr[pi];
            #pragma unroll
            for (int off = 32; off >= 1; off >>= 1) v += __shfl_xor(v, off, 64);
            if ((t & 63) == 0) wred[t >> 6][pi] = v;
        }
    }
    __syncthreads();
    if (t == 0) {
        const float scale = csh[3];
        float v[6];
        #pragma unroll
        for (int pi = 0; pi < 6; ++pi) {
            float sm = 0.f;
            #pragma unroll
            for (int w = 0; w < 8; ++w) sm += wred[w][pi];
            v[pi] = sm * scale;
        }
        float testv = v[0];
        #pragma unroll
        for (int pi = 1; pi < 6; ++pi) testv = fmaxf(testv, v[pi]);
        const float trainv = fmaxf(fmaxf(v[0], v[1]), v[3]);  // pairs (0,1),(0,2),(1,2)
        out[lf] = trainv;
        out[256 + lf] = testv;
        __threadfence();   // make out[] visible device-wide before the atomic
        const int old = __hip_atomic_fetch_add(counter, 1, __ATOMIC_ACQ_REL,
                                               __HIP_MEMORY_SCOPE_AGENT);
        lastf = (old == 255);
    }
    __syncthreads();

    // ---- last finished block computes the two scalar outputs ----
    if (lastf && t < 64) {
        const int ff = t & 31;
        const int base = (t >= 32) ? 256 : 0;      // lanes 0-31: train, 32-63: test
        float m = -FLT_MAX;
        #pragma unroll
        for (int ll = 0; ll < 8; ++ll) {
            const float val = __hip_atomic_load(&out[base + ll * 32 + ff],
                                                __ATOMIC_RELAXED, __HIP_MEMORY_SCOPE_AGENT);
            m = fmaxf(m, val);
        }
        #pragma unroll
        for (int off = 16; off >= 1; off >>= 1) m += __shfl_xor(m, off, 32);
        if (ff == 0) out[512 + (base ? 1 : 0)] = m * (1.0f / 32.0f);
    }
}

extern "C" void kernel_launch(void* const* d_in, const int* in_sizes, int n_in,
                              void* d_out, int out_size, void* d_ws, size_t ws_size,
                              hipStream_t stream) {
    (void)in_sizes; (void)n_in; (void)out_size; (void)ws_size;
    const float* matrix = (const float*)d_in[0];
    const float* params = (const float*)d_in[1];
    const int*   dlen   = (const int*)d_in[2];
    float* out = (float*)d_out;
    float* ws  = (float*)d_ws;
    float* PT   = ws + PT_OFF;
    float* sxg  = ws + SX_OFF;
    float* sxxg = ws + SXX_OFF;
    float* minp = ws + MIN_OFF;
    float* maxp = ws + MAX_OFF;
    int*   cnt  = (int*)(ws + CNT_OFF);

    hipLaunchKernelGGL(stage_prep, dim3(256), dim3(256), 0, stream,
                       matrix, params, PT, sxg, sxxg, minp, maxp, cnt);
    hipLaunchKernelGGL(stage_kde3, dim3(256), dim3(512), 0, stream,
                       PT, sxg, sxxg, minp, maxp, dlen, cnt, out);
}